// Round 12
// baseline (166.405 us; speedup 1.0000x reference)
//
#include <hip/hip_runtime.h>
#include <hip/hip_bf16.h>

#define CCH 384
#define HW2 3136
#define HH 56
#define WW 56
#define QMAX 7.0f
#define SCALE_MIN 2e-16f
#define YROWB 800        // ysh bytes per pos: 384 ci * 2B + 32B pad

typedef _Float16 half8 __attribute__((ext_vector_type(8)));
typedef float f32x4 __attribute__((ext_vector_type(4)));

// ---------------- quant kernels (Brevitas per-channel symmetric int4) -------

__global__ void quant_dw(const float* __restrict__ dw, float* __restrict__ dwq) {
    int c = blockIdx.x * blockDim.x + threadIdx.x;
    if (c >= CCH) return;
    float w[9];
    float amax = 0.f;
    #pragma unroll
    for (int j = 0; j < 9; ++j) {
        w[j] = dw[c * 9 + j];
        amax = fmaxf(amax, fabsf(w[j]));
    }
    float scale = fmaxf(amax / QMAX, SCALE_MIN);
    #pragma unroll
    for (int j = 0; j < 9; ++j) {
        float q = rintf(w[j] / scale);          // round half-even = jnp.round
        q = fminf(fmaxf(q, -QMAX), QMAX);
        dwq[c * 9 + j] = q * scale;
    }
}

// one block (64 threads) per output channel; fake-quant then pack fp16 into
// MFMA A-fragment layout: wpk[(ci/32)*24 + co/16][lane][8]
__global__ void quant_pw(const float* __restrict__ pw, _Float16* __restrict__ wpk) {
    int co = blockIdx.x;
    int lane = threadIdx.x;
    float w[6];
    float amax = 0.f;
    #pragma unroll
    for (int j = 0; j < 6; ++j) {
        w[j] = pw[co * CCH + lane + j * 64];
        amax = fmaxf(amax, fabsf(w[j]));
    }
    #pragma unroll
    for (int off = 32; off >= 1; off >>= 1)
        amax = fmaxf(amax, __shfl_xor(amax, off));
    float scale = fmaxf(amax / QMAX, SCALE_MIN);
    #pragma unroll
    for (int j = 0; j < 6; ++j) {
        int ci = lane + j * 64;
        float q = rintf(w[j] / scale);
        q = fminf(fmaxf(q, -QMAX), QMAX);
        float v = q * scale;
        int kk  = ci >> 5;
        int cis = ci & 31;
        int l   = (co & 15) | ((cis >> 3) << 4);
        int idx = (kk * 24 + (co >> 4)) * 512 + l * 8 + (cis & 7);
        wpk[idx] = (_Float16)v;
    }
}

// ---------------- fused v2: dw row -> LDS y-row -> MFMA pw ------------------
// Block: 256 thr (4 waves), one (n, output row h0). ONE barrier.
// Phase 1: wave wid computes y[ci = wid*96 .. +96][56 pos] via column-
//   streaming (lane = column, shuffle halo, coalesced 224B row loads, SGPR
//   weights); writes half8 octets (b128) into ysh[pos][ci], 16B-granule XOR
//   swizzle (^ (pos&7)<<4) -> ~conflict-free writes AND reads.
// Phase 2: r3-proven GEMM: 12 K-steps, wpk A-frags from global (L2-hot),
//   y B-frags via swizzled ds_read_b128, 24 MFMA/step, r3 epilogue with
//   pos<56 guard (pos 56..63 D-columns are garbage but never stored).

__global__ __launch_bounds__(256) void fused_kernel(
    const float* __restrict__ x, const float* __restrict__ dwq,
    const _Float16* __restrict__ wpk, const float* __restrict__ bias,
    float* __restrict__ out)
{
    __shared__ __align__(16) char ysh[HH * YROWB];   // 44.8 KB

    int bid = blockIdx.x;                  // 1792 = 8 XCDs * 224, chunked
    int wg = (bid & 7) * 224 + (bid >> 3);
    int n = wg / HH, h0 = wg % HH;

    const int tid  = threadIdx.x;
    const int lane = tid & 63;
    const int wid  = __builtin_amdgcn_readfirstlane(tid >> 6);

    // ---- phase 1: depthwise for row h0, this wave's 96 ci ----
    const int w = lane;
    const int wl = w < WW ? w : WW - 1;
    const bool act = (w < WW);
    const bool okm = (h0 > 0), okp = (h0 < HH - 1);

    const float* xn = x + (size_t)n * CCH * HW2;
    const int wci0 = wid * 96;

    #pragma unroll 2
    for (int oct = 0; oct < 12; ++oct) {
        const int ci0 = wci0 + oct * 8;
        float xm[8], xc[8], xp[8];
        #pragma unroll
        for (int j = 0; j < 8; ++j) {
            const float* xb = xn + (size_t)(ci0 + j) * HW2 + wl;
            xm[j] = okm ? xb[(h0 - 1) * WW] : 0.f;
            xc[j] = xb[h0 * WW];
            xp[j] = okp ? xb[(h0 + 1) * WW] : 0.f;
        }
        half8 hv;
        #pragma unroll
        for (int j = 0; j < 8; ++j) {
            const float* wq = dwq + (size_t)(ci0 + j) * 9;  // uniform -> s_load
            float a = 0.f;
            {
                float c = xm[j];
                float l = __shfl_up(c, 1), r = __shfl_down(c, 1);
                if (w == 0) l = 0.f;
                if (w == WW - 1) r = 0.f;
                a = fmaf(l, wq[0], a); a = fmaf(c, wq[1], a); a = fmaf(r, wq[2], a);
            }
            {
                float c = xc[j];
                float l = __shfl_up(c, 1), r = __shfl_down(c, 1);
                if (w == 0) l = 0.f;
                if (w == WW - 1) r = 0.f;
                a = fmaf(l, wq[3], a); a = fmaf(c, wq[4], a); a = fmaf(r, wq[5], a);
            }
            {
                float c = xp[j];
                float l = __shfl_up(c, 1), r = __shfl_down(c, 1);
                if (w == 0) l = 0.f;
                if (w == WW - 1) r = 0.f;
                a = fmaf(l, wq[6], a); a = fmaf(c, wq[7], a); a = fmaf(r, wq[8], a);
            }
            hv[j] = (_Float16)a;
        }
        if (act) {
            const int oct48 = wid * 12 + oct;        // global ci octet
            *(half8*)(ysh + w * YROWB + ((oct48 * 16) ^ ((w & 7) << 4))) = hv;
        }
    }
    __syncthreads();

    // ---- phase 2: GEMM (384 co x 384 ci x 64 pos) ----
    const int lco = lane & 15;
    const int lkg = lane >> 4;

    f32x4 acc[6][4];
    #pragma unroll
    for (int mc = 0; mc < 6; ++mc)
        #pragma unroll
        for (int np = 0; np < 4; ++np)
            acc[mc][np] = (f32x4){0.f, 0.f, 0.f, 0.f};

    for (int kk = 0; kk < 12; ++kk) {
        half8 wf[6];
        #pragma unroll
        for (int mc = 0; mc < 6; ++mc)
            wf[mc] = *(const half8*)(wpk + (size_t)(kk * 24 + wid * 6 + mc) * 512 + lane * 8);
        half8 yf[4];
        #pragma unroll
        for (int np = 0; np < 4; ++np) {
            const int pos = np * 16 + lco;
            yf[np] = *(const half8*)(ysh + pos * YROWB +
                                     ((kk * 64 + lkg * 16) ^ ((pos & 7) << 4)));
        }
        #pragma unroll
        for (int mc = 0; mc < 6; ++mc)
            #pragma unroll
            for (int np = 0; np < 4; ++np)
                acc[mc][np] = __builtin_amdgcn_mfma_f32_16x16x32_f16(
                    wf[mc], yf[np], acc[mc][np], 0, 0, 0);
    }

    // ---- epilogue: bias + store (row h0; pos<56 guard) ----
    float* ob = out + (size_t)n * CCH * HW2 + h0 * WW;
    #pragma unroll
    for (int mc = 0; mc < 6; ++mc) {
        #pragma unroll
        for (int r = 0; r < 4; ++r) {
            const int co = wid * 96 + mc * 16 + lkg * 4 + r;
            const float bv = bias[co];
            #pragma unroll
            for (int np = 0; np < 4; ++np) {
                const int pos = np * 16 + lco;
                if (np < 3 || lco < 8)
                    ob[(size_t)co * HW2 + pos] = acc[mc][np][r] + bv;
            }
        }
    }
}

// ---------------------------------------------------------------------------

extern "C" void kernel_launch(void* const* d_in, const int* in_sizes, int n_in,
                              void* d_out, int out_size, void* d_ws, size_t ws_size,
                              hipStream_t stream) {
    const float* x  = (const float*)d_in[0];
    const float* dw = (const float*)d_in[1];
    const float* pw = (const float*)d_in[2];
    const float* pb = (const float*)d_in[3];
    float* out = (float*)d_out;

    float*    dwq = (float*)d_ws;                         // 3456 f32
    _Float16* wpk = (_Float16*)(dwq + CCH * 9);           // 147456 fp16

    quant_dw<<<2, 256, 0, stream>>>(dw, dwq);
    quant_pw<<<CCH, 64, 0, stream>>>(pw, wpk);

    fused_kernel<<<1792, 256, 0, stream>>>(x, dwq, wpk, pb, out);
}

// Round 13
// 120.149 us; speedup vs baseline: 1.3850x; 1.3850x over previous
//
#include <hip/hip_runtime.h>
#include <hip/hip_bf16.h>

#define CCH 384
#define HW2 3136
#define HH 56
#define WW 56
#define QMAX 7.0f
#define SCALE_MIN 2e-16f
#define PB 49            // 64-pos blocks per image
#define YSLAB 512        // elems per (pb,c8) slab: 64 pos * 8 ci
#define YPB 24576        // 48 * 512 elems per pos-block

typedef _Float16 half8 __attribute__((ext_vector_type(8)));
typedef _Float16 half4v __attribute__((ext_vector_type(4)));
typedef float f32x4 __attribute__((ext_vector_type(4)));

#define GLOAD_LDS16(g, l) __builtin_amdgcn_global_load_lds( \
    (const __attribute__((address_space(1))) void*)(g), \
    (__attribute__((address_space(3))) void*)(l), 16, 0, 0)

// ---------------- merged quant kernel (Brevitas per-channel int4) -----------
// blocks 0..383: pointwise channel co=b (fake-quant + MFMA-layout pack)
// blocks 384..389: depthwise channels (b-384)*64 + tid

__global__ void quant_all(const float* __restrict__ dw, const float* __restrict__ pw,
                          float* __restrict__ dwq, _Float16* __restrict__ wpk) {
    int b = blockIdx.x;
    int lane = threadIdx.x;
    if (b < CCH) {
        const int co = b;
        float w[6];
        float amax = 0.f;
        #pragma unroll
        for (int j = 0; j < 6; ++j) {
            w[j] = pw[co * CCH + lane + j * 64];
            amax = fmaxf(amax, fabsf(w[j]));
        }
        #pragma unroll
        for (int off = 32; off >= 1; off >>= 1)
            amax = fmaxf(amax, __shfl_xor(amax, off));
        float scale = fmaxf(amax / QMAX, SCALE_MIN);
        #pragma unroll
        for (int j = 0; j < 6; ++j) {
            int ci = lane + j * 64;
            float q = rintf(w[j] / scale);
            q = fminf(fmaxf(q, -QMAX), QMAX);
            float v = q * scale;
            int kk  = ci >> 5;
            int cis = ci & 31;
            int l   = (co & 15) | ((cis >> 3) << 4);
            int idx = (kk * 24 + (co >> 4)) * 512 + l * 8 + (cis & 7);
            wpk[idx] = (_Float16)v;
        }
    } else {
        const int c = (b - CCH) * 64 + lane;
        if (c >= CCH) return;
        float w[9];
        float amax = 0.f;
        #pragma unroll
        for (int j = 0; j < 9; ++j) {
            w[j] = dw[c * 9 + j];
            amax = fmaxf(amax, fabsf(w[j]));
        }
        float scale = fmaxf(amax / QMAX, SCALE_MIN);
        #pragma unroll
        for (int j = 0; j < 9; ++j) {
            float q = rintf(w[j] / scale);      // round half-even = jnp.round
            q = fminf(fmaxf(q, -QMAX), QMAX);
            dwq[c * 9 + j] = q * scale;
        }
    }
}

// ---------------- kernel A (v7): column-streaming dw, 4ch/wave, 28 rows -----
// Wave-unit = (n, c8 slab, half 0/1, chgrp 0/1): 4 channels x 28 rows.
// Halved per-wave state (G-ring 36 VGPR, raw ring 16) -> ~2x occupancy vs v6.
// Lane = column; shuffle halo; depth-2 lookahead ring; SGPR weights.
// Stores: half4 (8B) into the [pos&63][8ci] octet, chgrp picks half.

struct G4 { float l[4], c[4], r[4]; };

__device__ __forceinline__ void dw_load(const float* __restrict__ xc,
                                        float (&xn)[4], int srow, int wl) {
    if ((unsigned)srow < (unsigned)HH) {
        #pragma unroll
        for (int ch = 0; ch < 4; ++ch)
            xn[ch] = xc[(size_t)ch * HW2 + srow * WW + wl];
    } else {
        #pragma unroll
        for (int ch = 0; ch < 4; ++ch) xn[ch] = 0.f;
    }
}

__device__ __forceinline__ void dw_shuf(const float (&xn)[4], G4& g, int w) {
    #pragma unroll
    for (int ch = 0; ch < 4; ++ch) {
        float v = xn[ch];
        float xl = __shfl_up(v, 1);
        float xr = __shfl_down(v, 1);
        g.c[ch] = v;
        g.l[ch] = (w == 0) ? 0.f : xl;
        g.r[ch] = (w == WW - 1) ? 0.f : xr;
    }
}

__device__ __forceinline__ void dw_cs(const G4& ga, const G4& gb, const G4& gc,
                                      const float (&wq)[36], _Float16* yn,
                                      int orow, int w, bool act) {
    half4v hv;
    #pragma unroll
    for (int ch = 0; ch < 4; ++ch) {
        const int b = ch * 9;
        float a;
        a = ga.l[ch] * wq[b + 0];
        a = fmaf(ga.c[ch], wq[b + 1], a);
        a = fmaf(ga.r[ch], wq[b + 2], a);
        a = fmaf(gb.l[ch], wq[b + 3], a);
        a = fmaf(gb.c[ch], wq[b + 4], a);
        a = fmaf(gb.r[ch], wq[b + 5], a);
        a = fmaf(gc.l[ch], wq[b + 6], a);
        a = fmaf(gc.c[ch], wq[b + 7], a);
        a = fmaf(gc.r[ch], wq[b + 8], a);
        hv[ch] = (_Float16)a;
    }
    if (act) {
        const int pos = orow * WW + w;
        *(half4v*)(yn + (size_t)(pos >> 6) * YPB + (pos & 63) * 8) = hv;
    }
}

#define DW_IT(K, RL, RS, GS, GA, GB, GC, DOLOAD)              \
    if (DOLOAD) dw_load(xc, RL, R0 + 3 + (K), wl);            \
    dw_shuf(RS, GS, w);                                       \
    dw_cs(GA, GB, GC, wq, yn, R0 + (K), w, act);

__global__ __launch_bounds__(128) void dw_kernel(
    const float* __restrict__ x, const float* __restrict__ dwq,
    _Float16* __restrict__ ypk)
{
    // 3072 blocks x 2 waves = 6144 wave-units; XCD-chunked swizzle
    int bid = blockIdx.x;
    int wg = (bid & 7) * 384 + (bid >> 3);
    int uid = wg * 2 + (threadIdx.x >> 6);
    int chgrp = uid & 1;
    int half = (uid >> 1) & 1;
    int t2 = uid >> 2;
    int c8 = t2 % 48, n = t2 / 48;
    const int R0 = half * 28;

    const int w = threadIdx.x & 63;
    const int wl = w < WW ? w : WW - 1;
    const bool act = (w < WW);

    const float* xc = x + ((size_t)n * CCH + (size_t)c8 * 8 + chgrp * 4) * HW2;
    _Float16* yn = ypk + (size_t)n * PB * YPB + (size_t)c8 * YSLAB + chgrp * 4;

    // weights -> SGPR (wave-uniform)
    float wq[36];
    const float* wsrc = dwq + (c8 * 8 + chgrp * 4) * 9;
    #pragma unroll
    for (int i = 0; i < 36; ++i)
        wq[i] = __uint_as_float(
            __builtin_amdgcn_readfirstlane(__float_as_uint(wsrc[i])));

    float r0[4], r1[4], r2[4], r3[4];
    G4 g0, g1, g2;

    // prologue: rows R0-1..R0+2 as one independent batch
    if (R0 == 0) {
        #pragma unroll
        for (int ch = 0; ch < 4; ++ch) r0[ch] = 0.f;
    } else {
        dw_load(xc, r0, R0 - 1, wl);
    }
    dw_load(xc, r1, R0, wl);
    dw_load(xc, r2, R0 + 1, wl);
    dw_load(xc, r3, R0 + 2, wl);
    dw_shuf(r0, g0, w);
    dw_shuf(r1, g1, w);

    DW_IT(0,  r0, r2, g2, g0, g1, g2, true)
    DW_IT(1,  r1, r3, g0, g1, g2, g0, true)
    DW_IT(2,  r2, r0, g1, g2, g0, g1, true)
    DW_IT(3,  r3, r1, g2, g0, g1, g2, true)
    DW_IT(4,  r0, r2, g0, g1, g2, g0, true)
    DW_IT(5,  r1, r3, g1, g2, g0, g1, true)
    DW_IT(6,  r2, r0, g2, g0, g1, g2, true)
    DW_IT(7,  r3, r1, g0, g1, g2, g0, true)
    DW_IT(8,  r0, r2, g1, g2, g0, g1, true)
    DW_IT(9,  r1, r3, g2, g0, g1, g2, true)
    DW_IT(10, r2, r0, g0, g1, g2, g0, true)
    DW_IT(11, r3, r1, g1, g2, g0, g1, true)
    DW_IT(12, r0, r2, g2, g0, g1, g2, true)
    DW_IT(13, r1, r3, g0, g1, g2, g0, true)
    DW_IT(14, r2, r0, g1, g2, g0, g1, true)
    DW_IT(15, r3, r1, g2, g0, g1, g2, true)
    DW_IT(16, r0, r2, g0, g1, g2, g0, true)
    DW_IT(17, r1, r3, g1, g2, g0, g1, true)
    DW_IT(18, r2, r0, g2, g0, g1, g2, true)
    DW_IT(19, r3, r1, g0, g1, g2, g0, true)
    DW_IT(20, r0, r2, g1, g2, g0, g1, true)
    DW_IT(21, r1, r3, g2, g0, g1, g2, true)
    DW_IT(22, r2, r0, g0, g1, g2, g0, true)
    DW_IT(23, r3, r1, g1, g2, g0, g1, true)
    DW_IT(24, r0, r2, g2, g0, g1, g2, true)
    DW_IT(25, r1, r3, g0, g1, g2, g0, true)
    DW_IT(26, r2, r0, g1, g2, g0, g1, false)
    DW_IT(27, r3, r1, g2, g0, g1, g2, false)
}

// ---------------- kernel B: pointwise GEMM (384co x 384ci x 64pos/blk) ------
// Stage packed y tile (48KB) via global_load_lds, one barrier, pure
// ds_read_b128 + MFMA, scalar epilogue. (r3-proven, unchanged.)

__global__ __launch_bounds__(256) void pw_kernel(
    const _Float16* __restrict__ ypk, const _Float16* __restrict__ wpk,
    const float* __restrict__ bias, float* __restrict__ out)
{
    __shared__ __align__(16) _Float16 ysh[YPB];   // 48 KB

    int bid = blockIdx.x;                 // 1568 = 8 * 196
    int wg = (bid & 7) * 196 + (bid >> 3);
    int n = wg / PB, pb = wg % PB;

    const int t = threadIdx.x;
    const int lane = t & 63;
    const int g = __builtin_amdgcn_readfirstlane(t >> 6);

    // ---- stage y tile: identity copy of the packed 48KB blob ----
    const _Float16* yg = ypk + (size_t)(n * PB + pb) * YPB;
    #pragma unroll
    for (int j = 0; j < 12; ++j) {
        GLOAD_LDS16(yg + (j * 256 + t) * 8,
                    ysh + (size_t)(j * 256 + (t & 192)) * 8);
    }
    __syncthreads();

    // ---- K-loop ----
    const int lco = lane & 15;
    const int lkg = lane >> 4;
    const int cbf = g * 6;

    f32x4 acc[6][4];
    #pragma unroll
    for (int mc = 0; mc < 6; ++mc)
        #pragma unroll
        for (int np = 0; np < 4; ++np)
            acc[mc][np] = (f32x4){0.f, 0.f, 0.f, 0.f};

    for (int kk = 0; kk < 12; ++kk) {
        half8 wf[6];
        #pragma unroll
        for (int mc = 0; mc < 6; ++mc)
            wf[mc] = *(const half8*)(wpk + (size_t)(kk * 24 + cbf + mc) * 512 + lane * 8);
        half8 yf[4];
        #pragma unroll
        for (int np = 0; np < 4; ++np)
            yf[np] = *(const half8*)(ysh + kk * 2048 + lkg * 512 + (np * 16 + lco) * 8);
        #pragma unroll
        for (int mc = 0; mc < 6; ++mc)
            #pragma unroll
            for (int np = 0; np < 4; ++np)
                acc[mc][np] = __builtin_amdgcn_mfma_f32_16x16x32_f16(
                    wf[mc], yf[np], acc[mc][np], 0, 0, 0);
    }

    // ---- epilogue: bias + store ----
    float* ob = out + (size_t)n * CCH * HW2 + (size_t)pb * 64;
    #pragma unroll
    for (int mc = 0; mc < 6; ++mc) {
        #pragma unroll
        for (int r = 0; r < 4; ++r) {
            const int co = g * 96 + mc * 16 + lkg * 4 + r;
            const float bv = bias[co];
            #pragma unroll
            for (int np = 0; np < 4; ++np)
                ob[(size_t)co * HW2 + np * 16 + lco] = acc[mc][np][r] + bv;
        }
    }
}

// ---------------------------------------------------------------------------

extern "C" void kernel_launch(void* const* d_in, const int* in_sizes, int n_in,
                              void* d_out, int out_size, void* d_ws, size_t ws_size,
                              hipStream_t stream) {
    const float* x  = (const float*)d_in[0];
    const float* dw = (const float*)d_in[1];
    const float* pw = (const float*)d_in[2];
    const float* pb = (const float*)d_in[3];
    float* out = (float*)d_out;

    float*    dwq = (float*)d_ws;                         // 3456 f32
    _Float16* wpk = (_Float16*)(dwq + CCH * 9);           // 147456 fp16
    _Float16* ypk = wpk + (size_t)CCH * CCH;              // 38.5M fp16 (77 MB)

    quant_all<<<CCH + 6, 64, 0, stream>>>(dw, pw, dwq, wpk);

    dw_kernel<<<3072, 128, 0, stream>>>(x, dwq, ypk);
    pw_kernel<<<1568, 256, 0, stream>>>(ypk, wpk, pb, out);
}

// Round 14
// 114.868 us; speedup vs baseline: 1.4487x; 1.0460x over previous
//
#include <hip/hip_runtime.h>
#include <hip/hip_bf16.h>

#define CCH 384
#define HW2 3136
#define HH 56
#define WW 56
#define QMAX 7.0f
#define SCALE_MIN 2e-16f
#define PB 49            // 64-pos blocks per image
#define YSLAB 512        // elems per (pb,c8) slab: 64 pos * 8 ci
#define YPB 24576        // 48 * 512 elems per pos-block

typedef _Float16 half8 __attribute__((ext_vector_type(8)));
typedef float f32x4 __attribute__((ext_vector_type(4)));

#define GLOAD_LDS16(g, l) __builtin_amdgcn_global_load_lds( \
    (const __attribute__((address_space(1))) void*)(g), \
    (__attribute__((address_space(3))) void*)(l), 16, 0, 0)

// ---------------- merged quant kernel (Brevitas per-channel int4) -----------
// blocks 0..383: pointwise channel co=b (fake-quant + MFMA-layout pack)
// blocks 384..389: depthwise channels (b-384)*64 + tid

__global__ void quant_all(const float* __restrict__ dw, const float* __restrict__ pw,
                          float* __restrict__ dwq, _Float16* __restrict__ wpk) {
    int b = blockIdx.x;
    int lane = threadIdx.x;
    if (b < CCH) {
        const int co = b;
        float w[6];
        float amax = 0.f;
        #pragma unroll
        for (int j = 0; j < 6; ++j) {
            w[j] = pw[co * CCH + lane + j * 64];
            amax = fmaxf(amax, fabsf(w[j]));
        }
        #pragma unroll
        for (int off = 32; off >= 1; off >>= 1)
            amax = fmaxf(amax, __shfl_xor(amax, off));
        float scale = fmaxf(amax / QMAX, SCALE_MIN);
        #pragma unroll
        for (int j = 0; j < 6; ++j) {
            int ci = lane + j * 64;
            float q = rintf(w[j] / scale);
            q = fminf(fmaxf(q, -QMAX), QMAX);
            float v = q * scale;
            int kk  = ci >> 5;
            int cis = ci & 31;
            int l   = (co & 15) | ((cis >> 3) << 4);
            int idx = (kk * 24 + (co >> 4)) * 512 + l * 8 + (cis & 7);
            wpk[idx] = (_Float16)v;
        }
    } else {
        const int c = (b - CCH) * 64 + lane;
        if (c >= CCH) return;
        float w[9];
        float amax = 0.f;
        #pragma unroll
        for (int j = 0; j < 9; ++j) {
            w[j] = dw[c * 9 + j];
            amax = fmaxf(amax, fabsf(w[j]));
        }
        float scale = fmaxf(amax / QMAX, SCALE_MIN);
        #pragma unroll
        for (int j = 0; j < 9; ++j) {
            float q = rintf(w[j] / scale);      // round half-even = jnp.round
            q = fminf(fmaxf(q, -QMAX), QMAX);
            dwq[c * 9 + j] = q * scale;
        }
    }
}

// ---------------- kernel A (v6.2): column-streaming dw, L2-grouped ----------
// Identical compute to r10's v6.1 (8ch/wave, 14-row quarter, depth-2 ring,
// shuffle halo, SGPR weights). ONE change: wave-unit decomposition is
// (n, half, c8, q2) so the ~96 concurrently-resident units per XCD cover a
// HALF-image (2.4MB x + 1.2MB y < 4MB L2) -> x loads hit L2 (~200cyc), which
// the depth-2 lookahead fully covers, instead of L3 (~600cyc), which it
// doesn't.

struct G8 { float l[8], c[8], r[8]; };

__device__ __forceinline__ void dw_load(const float* __restrict__ xc,
                                        float (&xn)[8], int srow, int wl) {
    if ((unsigned)srow < (unsigned)HH) {
        #pragma unroll
        for (int ch = 0; ch < 8; ++ch)
            xn[ch] = xc[(size_t)ch * HW2 + srow * WW + wl];
    } else {
        #pragma unroll
        for (int ch = 0; ch < 8; ++ch) xn[ch] = 0.f;
    }
}

__device__ __forceinline__ void dw_shuf(const float (&xn)[8], G8& g, int w) {
    #pragma unroll
    for (int ch = 0; ch < 8; ++ch) {
        float v = xn[ch];
        float xl = __shfl_up(v, 1);
        float xr = __shfl_down(v, 1);
        g.c[ch] = v;
        g.l[ch] = (w == 0) ? 0.f : xl;
        g.r[ch] = (w == WW - 1) ? 0.f : xr;
    }
}

__device__ __forceinline__ void dw_cs(const G8& ga, const G8& gb, const G8& gc,
                                      const float (&wq)[72], _Float16* yn,
                                      int orow, int w, bool act) {
    half8 hv;
    #pragma unroll
    for (int ch = 0; ch < 8; ++ch) {
        const int b = ch * 9;
        float a;
        a = ga.l[ch] * wq[b + 0];
        a = fmaf(ga.c[ch], wq[b + 1], a);
        a = fmaf(ga.r[ch], wq[b + 2], a);
        a = fmaf(gb.l[ch], wq[b + 3], a);
        a = fmaf(gb.c[ch], wq[b + 4], a);
        a = fmaf(gb.r[ch], wq[b + 5], a);
        a = fmaf(gc.l[ch], wq[b + 6], a);
        a = fmaf(gc.c[ch], wq[b + 7], a);
        a = fmaf(gc.r[ch], wq[b + 8], a);
        hv[ch] = (_Float16)a;
    }
    if (act) {
        const int pos = orow * WW + w;
        *(half8*)(yn + (size_t)(pos >> 6) * YPB + (pos & 63) * 8) = hv;
    }
}

// iter k: load row R0+3+k -> RL; shuffle RS (row R0+1+k) -> GS;
// compute output row R0+k from (GA,GB,GC).
#define DW_IT(K, RL, RS, GS, GA, GB, GC, DOLOAD)              \
    if (DOLOAD) dw_load(xc, RL, R0 + 3 + (K), wl);            \
    dw_shuf(RS, GS, w);                                       \
    dw_cs(GA, GB, GC, wq, yn, R0 + (K), w, act);

__global__ __launch_bounds__(128) void dw_kernel(
    const float* __restrict__ x, const float* __restrict__ dwq,
    _Float16* __restrict__ ypk)
{
    // 3072 blocks x 2 waves = 6144 wave-units; XCD-chunked swizzle.
    // uid = (((n*2 + half)*48) + c8)*2 + q2  -> half-image L2 grouping.
    int bid = blockIdx.x;
    int wg = (bid & 7) * 384 + (bid >> 3);
    int uid = wg * 2 + (threadIdx.x >> 6);
    int q2 = uid & 1;
    int t = uid >> 1;
    int c8 = t % 48;
    int t2 = t / 48;
    int hf = t2 & 1;
    int n = t2 >> 1;
    const int R0 = (hf * 2 + q2) * 14;

    const int w = threadIdx.x & 63;
    const int wl = w < WW ? w : WW - 1;
    const bool act = (w < WW);

    const float* xc = x + ((size_t)n * CCH + (size_t)c8 * 8) * HW2;
    _Float16* yn = ypk + (size_t)n * PB * YPB + (size_t)c8 * YSLAB;

    // weights -> SGPR (wave-uniform)
    float wq[72];
    const float* wsrc = dwq + c8 * 72;
    #pragma unroll
    for (int i = 0; i < 72; ++i)
        wq[i] = __uint_as_float(
            __builtin_amdgcn_readfirstlane(__float_as_uint(wsrc[i])));

    float r0[8], r1[8], r2[8], r3[8];
    G8 g0, g1, g2;

    // prologue: issue rows R0-1..R0+2 as one independent batch
    if (R0 == 0) {
        #pragma unroll
        for (int ch = 0; ch < 8; ++ch) r0[ch] = 0.f;
    } else {
        dw_load(xc, r0, R0 - 1, wl);
    }
    dw_load(xc, r1, R0, wl);
    dw_load(xc, r2, R0 + 1, wl);
    dw_load(xc, r3, R0 + 2, wl);
    dw_shuf(r0, g0, w);
    dw_shuf(r1, g1, w);

    DW_IT(0,  r0, r2, g2, g0, g1, g2, true)
    DW_IT(1,  r1, r3, g0, g1, g2, g0, true)
    DW_IT(2,  r2, r0, g1, g2, g0, g1, true)
    DW_IT(3,  r3, r1, g2, g0, g1, g2, true)
    DW_IT(4,  r0, r2, g0, g1, g2, g0, true)
    DW_IT(5,  r1, r3, g1, g2, g0, g1, true)
    DW_IT(6,  r2, r0, g2, g0, g1, g2, true)
    DW_IT(7,  r3, r1, g0, g1, g2, g0, true)
    DW_IT(8,  r0, r2, g1, g2, g0, g1, true)
    DW_IT(9,  r1, r3, g2, g0, g1, g2, true)
    DW_IT(10, r2, r0, g0, g1, g2, g0, true)
    DW_IT(11, r3, r1, g1, g2, g0, g1, true)
    DW_IT(12, r0, r2, g2, g0, g1, g2, false)
    DW_IT(13, r1, r3, g0, g1, g2, g0, false)
}

// ---------------- kernel B: pointwise GEMM (384co x 384ci x 64pos/blk) ------
// Stage packed y tile (48KB) via global_load_lds, one barrier, pure
// ds_read_b128 + MFMA, scalar epilogue. (r3-proven, unchanged.)

__global__ __launch_bounds__(256) void pw_kernel(
    const _Float16* __restrict__ ypk, const _Float16* __restrict__ wpk,
    const float* __restrict__ bias, float* __restrict__ out)
{
    __shared__ __align__(16) _Float16 ysh[YPB];   // 48 KB

    int bid = blockIdx.x;                 // 1568 = 8 * 196
    int wg = (bid & 7) * 196 + (bid >> 3);
    int n = wg / PB, pb = wg % PB;

    const int t = threadIdx.x;
    const int lane = t & 63;
    const int g = __builtin_amdgcn_readfirstlane(t >> 6);

    // ---- stage y tile: identity copy of the packed 48KB blob ----
    const _Float16* yg = ypk + (size_t)(n * PB + pb) * YPB;
    #pragma unroll
    for (int j = 0; j < 12; ++j) {
        GLOAD_LDS16(yg + (j * 256 + t) * 8,
                    ysh + (size_t)(j * 256 + (t & 192)) * 8);
    }
    __syncthreads();

    // ---- K-loop ----
    const int lco = lane & 15;
    const int lkg = lane >> 4;
    const int cbf = g * 6;

    f32x4 acc[6][4];
    #pragma unroll
    for (int mc = 0; mc < 6; ++mc)
        #pragma unroll
        for (int np = 0; np < 4; ++np)
            acc[mc][np] = (f32x4){0.f, 0.f, 0.f, 0.f};

    for (int kk = 0; kk < 12; ++kk) {
        half8 wf[6];
        #pragma unroll
        for (int mc = 0; mc < 6; ++mc)
            wf[mc] = *(const half8*)(wpk + (size_t)(kk * 24 + cbf + mc) * 512 + lane * 8);
        half8 yf[4];
        #pragma unroll
        for (int np = 0; np < 4; ++np)
            yf[np] = *(const half8*)(ysh + kk * 2048 + lkg * 512 + (np * 16 + lco) * 8);
        #pragma unroll
        for (int mc = 0; mc < 6; ++mc)
            #pragma unroll
            for (int np = 0; np < 4; ++np)
                acc[mc][np] = __builtin_amdgcn_mfma_f32_16x16x32_f16(
                    wf[mc], yf[np], acc[mc][np], 0, 0, 0);
    }

    // ---- epilogue: bias + store ----
    float* ob = out + (size_t)n * CCH * HW2 + (size_t)pb * 64;
    #pragma unroll
    for (int mc = 0; mc < 6; ++mc) {
        #pragma unroll
        for (int r = 0; r < 4; ++r) {
            const int co = g * 96 + mc * 16 + lkg * 4 + r;
            const float bv = bias[co];
            #pragma unroll
            for (int np = 0; np < 4; ++np)
                ob[(size_t)co * HW2 + np * 16 + lco] = acc[mc][np][r] + bv;
        }
    }
}

// ---------------------------------------------------------------------------

extern "C" void kernel_launch(void* const* d_in, const int* in_sizes, int n_in,
                              void* d_out, int out_size, void* d_ws, size_t ws_size,
                              hipStream_t stream) {
    const float* x  = (const float*)d_in[0];
    const float* dw = (const float*)d_in[1];
    const float* pw = (const float*)d_in[2];
    const float* pb = (const float*)d_in[3];
    float* out = (float*)d_out;

    float*    dwq = (float*)d_ws;                         // 3456 f32
    _Float16* wpk = (_Float16*)(dwq + CCH * 9);           // 147456 fp16
    _Float16* ypk = wpk + (size_t)CCH * CCH;              // 38.5M fp16 (77 MB)

    quant_all<<<CCH + 6, 64, 0, stream>>>(dw, pw, dwq, wpk);

    dw_kernel<<<3072, 128, 0, stream>>>(x, dwq, ypk);
    pw_kernel<<<1568, 256, 0, stream>>>(ypk, wpk, pb, out);
}